// Round 2
// baseline (64.386 us; speedup 1.0000x reference)
//
#include <hip/hip_runtime.h>
#include <math.h>

#define ALPHA 0.001f
#define GAMMA 0.01f
#define DD 784
#define TD 1568          // 2*D
#define MM 256
#define BB 1024
#define NCLS 10

// ws layout (floats):
//   [0..255]    per-block partial min of x
//   [256..511]  per-block partial max of x
//   [512..767]  scale[m] = committed ? 1/denom : -1

__global__ __launch_bounds__(256) void k_minmax(const float* __restrict__ x,
                                                float* __restrict__ ws) {
  const float4* x4 = (const float4*)x;
  const int n4 = BB * DD / 4;  // 200704
  int tid = blockIdx.x * 256 + threadIdx.x;
  float mn = 1e30f, mx = -1e30f;
  for (int i = tid; i < n4; i += 256 * 256) {
    float4 v = x4[i];
    mn = fminf(mn, fminf(fminf(v.x, v.y), fminf(v.z, v.w)));
    mx = fmaxf(mx, fmaxf(fmaxf(v.x, v.y), fmaxf(v.z, v.w)));
  }
#pragma unroll
  for (int off = 32; off; off >>= 1) {
    mn = fminf(mn, __shfl_xor(mn, off, 64));
    mx = fmaxf(mx, __shfl_xor(mx, off, 64));
  }
  __shared__ float smn[4], smx[4];
  int lane = threadIdx.x & 63, wid = threadIdx.x >> 6;
  if (lane == 0) { smn[wid] = mn; smx[wid] = mx; }
  __syncthreads();
  if (threadIdx.x == 0) {
    mn = fminf(fminf(smn[0], smn[1]), fminf(smn[2], smn[3]));
    mx = fmaxf(fmaxf(smx[0], smx[1]), fmaxf(smx[2], smx[3]));
    ws[blockIdx.x] = mn;
    ws[256 + blockIdx.x] = mx;
  }
}

__global__ __launch_bounds__(64) void k_denom(const float* __restrict__ T,
                                              const int* __restrict__ committed,
                                              const int* __restrict__ counts,
                                              float* __restrict__ scale_out) {
  int m = blockIdx.x;
  int lane = threadIdx.x;
  const float4* t4 = (const float4*)(T + m * TD);
  float s = 0.f;
  for (int i = lane; i < TD / 4; i += 64) {   // 392 float4
    float4 v = t4[i];
    s += (v.x + v.y) + (v.z + v.w);
  }
#pragma unroll
  for (int off = 32; off; off >>= 1) s += __shfl_xor(s, off, 64);
  if (lane == 0) {
    float denom = ALPHA + s + GAMMA * (float)counts[m];
    scale_out[m] = committed[m] ? (1.0f / denom) : -1.0f;
  }
}

__global__ __launch_bounds__(512) void k_main(const float* __restrict__ x,
                                              const float* __restrict__ T,
                                              const int* __restrict__ labels,
                                              const float* __restrict__ ws,
                                              float* __restrict__ out) {
  __shared__ float coded[4][TD];      // 25088 B
  __shared__ float4 psum[MM];         // 4096 B
  __shared__ int clsmax[4 * NCLS];
  __shared__ float wred[16];
  __shared__ float s_stats[2];

  int tid = threadIdx.x;
  int lane = tid & 63, wid = tid >> 6;

  // ---- phase 0: finish global min/max reduction from 256 partials ----
  float mn = (tid < 256) ? ws[tid] : 1e30f;
  float mx = (tid < 256) ? ws[256 + tid] : -1e30f;
#pragma unroll
  for (int off = 32; off; off >>= 1) {
    mn = fminf(mn, __shfl_xor(mn, off, 64));
    mx = fmaxf(mx, __shfl_xor(mx, off, 64));
  }
  if (lane == 0) { wred[wid] = mn; wred[8 + wid] = mx; }
  if (tid < 4 * NCLS) clsmax[tid] = -1;   // sentinel: "no committed template seen"
  __syncthreads();
  if (tid == 0) {
    mn = wred[0]; mx = wred[8];
#pragma unroll
    for (int w = 1; w < 8; ++w) { mn = fminf(mn, wred[w]); mx = fmaxf(mx, wred[8 + w]); }
    s_stats[0] = mn;
    s_stats[1] = 1.0f / (mx - mn + 1e-10f);
  }
  __syncthreads();
  float fmn = s_stats[0], finv = s_stats[1];

  // ---- phase 1: build complement-coded rows in LDS ----
  int row0 = blockIdx.x * 4;
  const float4* xr = (const float4*)(x + row0 * DD);  // 4 rows contiguous = 784 float4
  for (int idx = tid; idx < 4 * DD / 4; idx += 512) {
    int r = idx / (DD / 4);
    int c = idx - r * (DD / 4);
    float4 v = xr[idx];
    float a = (v.x - fmn) * finv, b = (v.y - fmn) * finv;
    float cc = (v.z - fmn) * finv, d = (v.w - fmn) * finv;
    int j = c * 4;
    coded[r][j] = a;  coded[r][j + 1] = b;  coded[r][j + 2] = cc;  coded[r][j + 3] = d;
    coded[r][DD + j] = 1.f - a;  coded[r][DD + j + 1] = 1.f - b;
    coded[r][DD + j + 2] = 1.f - cc;  coded[r][DD + j + 3] = 1.f - d;
  }
  __syncthreads();

  // ---- phase 2: fuzzy-AND sums: thread = (template m, j-half) ----
  int m = tid & 255;
  int jhalf = tid >> 8;   // 0 or 1
  const float4* t4 = (const float4*)(T + m * TD);
  const float4* c0 = (const float4*)coded[0];
  const float4* c1 = (const float4*)coded[1];
  const float4* c2 = (const float4*)coded[2];
  const float4* c3 = (const float4*)coded[3];
  float4 a0 = make_float4(0, 0, 0, 0), a1 = a0, a2 = a0, a3 = a0;
  int j0 = jhalf * (TD / 8);   // 0 or 196 (float4 units)
#pragma unroll 4
  for (int j = j0; j < j0 + TD / 8; ++j) {
    float4 tv = t4[j];
    float4 v;
    v = c0[j];
    a0.x += fminf(v.x, tv.x); a0.y += fminf(v.y, tv.y);
    a0.z += fminf(v.z, tv.z); a0.w += fminf(v.w, tv.w);
    v = c1[j];
    a1.x += fminf(v.x, tv.x); a1.y += fminf(v.y, tv.y);
    a1.z += fminf(v.z, tv.z); a1.w += fminf(v.w, tv.w);
    v = c2[j];
    a2.x += fminf(v.x, tv.x); a2.y += fminf(v.y, tv.y);
    a2.z += fminf(v.z, tv.z); a2.w += fminf(v.w, tv.w);
    v = c3[j];
    a3.x += fminf(v.x, tv.x); a3.y += fminf(v.y, tv.y);
    a3.z += fminf(v.z, tv.z); a3.w += fminf(v.w, tv.w);
  }
  float s0 = (a0.x + a0.y) + (a0.z + a0.w);
  float s1 = (a1.x + a1.y) + (a1.z + a1.w);
  float s2 = (a2.x + a2.y) + (a2.z + a2.w);
  float s3 = (a3.x + a3.y) + (a3.z + a3.w);

  if (jhalf == 1) psum[m] = make_float4(s0, s1, s2, s3);
  __syncthreads();
  if (jhalf == 0) {
    float4 p = psum[m];
    s0 += p.x; s1 += p.y; s2 += p.z; s3 += p.w;
    float sc = ws[512 + m];
    if (sc > 0.f) {   // committed
      int cls = labels[m];
      atomicMax(&clsmax[cls],             __float_as_int(s0 * sc));
      atomicMax(&clsmax[NCLS + cls],      __float_as_int(s1 * sc));
      atomicMax(&clsmax[2 * NCLS + cls],  __float_as_int(s2 * sc));
      atomicMax(&clsmax[3 * NCLS + cls],  __float_as_int(s3 * sc));
    }
  }
  __syncthreads();
  if (tid < 4 * NCLS) {
    int bits = clsmax[tid];
    int r = tid / NCLS, c = tid - r * NCLS;
    out[(row0 + r) * NCLS + c] = (bits == -1) ? -INFINITY : __int_as_float(bits);
  }
}

extern "C" void kernel_launch(void* const* d_in, const int* in_sizes, int n_in,
                              void* d_out, int out_size, void* d_ws, size_t ws_size,
                              hipStream_t stream) {
  const float* x = (const float*)d_in[0];
  const float* T = (const float*)d_in[1];
  const int* committed = (const int*)d_in[2];
  const int* labels = (const int*)d_in[3];
  const int* counts = (const int*)d_in[4];
  float* out = (float*)d_out;
  float* ws = (float*)d_ws;

  k_minmax<<<dim3(256), dim3(256), 0, stream>>>(x, ws);
  k_denom<<<dim3(256), dim3(64), 0, stream>>>(T, committed, counts, ws + 512);
  k_main<<<dim3(256), dim3(512), 0, stream>>>(x, T, labels, ws, out);
}

// Round 3
// 63.298 us; speedup vs baseline: 1.0172x; 1.0172x over previous
//
#include <hip/hip_runtime.h>
#include <math.h>

#define ALPHA 0.001f
#define GAMMA 0.01f
#define DD 784
#define TD 1568          // 2*D
#define ND4 392          // TD/4
#define PAD4 393         // padded row stride in float4 units
#define MM 256
#define BB 1024
#define NCLS 10

// ws layout (floats):
//   [0..255]    per-block partial min of x
//   [256..511]  per-block partial max of x
//   [512..767]  scale[m] = committed ? 1/denom : -1

__global__ __launch_bounds__(256) void k_minmax(const float* __restrict__ x,
                                                float* __restrict__ ws,
                                                int* __restrict__ out_bits) {
  const float4* x4 = (const float4*)x;
  const int n4 = BB * DD / 4;  // 200704
  int tid = blockIdx.x * 256 + threadIdx.x;

  // init output to -inf bits (poison is not re-applied between replays)
  if (tid < BB * NCLS) out_bits[tid] = 0xFF800000;

  float mn = 1e30f, mx = -1e30f;
  for (int i = tid; i < n4; i += 256 * 256) {
    float4 v = x4[i];
    mn = fminf(mn, fminf(fminf(v.x, v.y), fminf(v.z, v.w)));
    mx = fmaxf(mx, fmaxf(fmaxf(v.x, v.y), fmaxf(v.z, v.w)));
  }
#pragma unroll
  for (int off = 32; off; off >>= 1) {
    mn = fminf(mn, __shfl_xor(mn, off, 64));
    mx = fmaxf(mx, __shfl_xor(mx, off, 64));
  }
  __shared__ float smn[4], smx[4];
  int lane = threadIdx.x & 63, wid = threadIdx.x >> 6;
  if (lane == 0) { smn[wid] = mn; smx[wid] = mx; }
  __syncthreads();
  if (threadIdx.x == 0) {
    mn = fminf(fminf(smn[0], smn[1]), fminf(smn[2], smn[3]));
    mx = fmaxf(fmaxf(smx[0], smx[1]), fmaxf(smx[2], smx[3]));
    ws[blockIdx.x] = mn;
    ws[256 + blockIdx.x] = mx;
  }
}

__global__ __launch_bounds__(64) void k_denom(const float* __restrict__ T,
                                              const int* __restrict__ committed,
                                              const int* __restrict__ counts,
                                              float* __restrict__ scale_out) {
  int m = blockIdx.x;
  int lane = threadIdx.x;
  const float4* t4 = (const float4*)(T + m * TD);
  float s = 0.f;
  for (int i = lane; i < ND4; i += 64) {
    float4 v = t4[i];
    s += (v.x + v.y) + (v.z + v.w);
  }
#pragma unroll
  for (int off = 32; off; off >>= 1) s += __shfl_xor(s, off, 64);
  if (lane == 0) {
    float denom = ALPHA + s + GAMMA * (float)counts[m];
    scale_out[m] = committed[m] ? (1.0f / denom) : -1.0f;
  }
}

// grid: 2048 blocks = 256 row-groups x 8 template-groups; 512 threads = 8 waves.
// wave = 4 templates x 4 rows; lane = (r = lane>>4, jl = lane&15).
__global__ __launch_bounds__(512) void k_main(const float* __restrict__ x,
                                              const float* __restrict__ T,
                                              const int* __restrict__ labels,
                                              const float* __restrict__ ws,
                                              int* __restrict__ out_bits) {
  __shared__ float coded[4 * PAD4 * 4];   // 4 rows x 393 float4 = 25152 B
  __shared__ int clsmax[4][NCLS];
  __shared__ float wred[16];
  __shared__ float s_stats[2];

  int tid = threadIdx.x;
  int lane = tid & 63, wid = tid >> 6;
  int rowgroup = blockIdx.x >> 3;
  int tgroup = blockIdx.x & 7;
  int row0 = rowgroup * 4;
  int m0 = tgroup * 32 + wid * 4;   // this wave's first template

  // ---- phase 0: finish global min/max reduction from 512 partials ----
  float mn = (tid < 256) ? ws[tid] : 1e30f;
  float mx = (tid < 256) ? ws[256 + tid] : -1e30f;
#pragma unroll
  for (int off = 32; off; off >>= 1) {
    mn = fminf(mn, __shfl_xor(mn, off, 64));
    mx = fmaxf(mx, __shfl_xor(mx, off, 64));
  }
  if (lane == 0) { wred[wid] = mn; wred[8 + wid] = mx; }
  if (tid < 4 * NCLS) clsmax[tid / NCLS][tid % NCLS] = 0xFF800000;
  __syncthreads();
  if (tid == 0) {
    mn = wred[0]; mx = wred[8];
#pragma unroll
    for (int w = 1; w < 8; ++w) { mn = fminf(mn, wred[w]); mx = fmaxf(mx, wred[8 + w]); }
    s_stats[0] = mn;
    s_stats[1] = 1.0f / (mx - mn + 1e-10f);
  }
  __syncthreads();
  float fmn = s_stats[0], finv = s_stats[1];

  // ---- phase 1: build complement-coded rows in LDS (padded stride) ----
  const float4* xr = (const float4*)(x + row0 * DD);  // 4*196 = 784 float4
  float4* cshr = (float4*)coded;
  for (int idx = tid; idx < 4 * (DD / 4); idx += 512) {
    int r = idx / (DD / 4);
    int c = idx - r * (DD / 4);
    float4 v = xr[idx];
    float a = (v.x - fmn) * finv, b = (v.y 
 - fmn) * finv;
    float cc = (v.z - fmn) * finv, d = (v.w - fmn) * finv;
    cshr[r * PAD4 + c] = make_float4(a, b, cc, d);
    cshr[r * PAD4 + (DD / 4) + c] = make_float4(1.f - a, 1.f - b, 1.f - cc, 1.f - d);
  }
  __syncthreads();

  // ---- phase 2: fuzzy-AND main loop ----
  int r = lane >> 4;        // row within group
  int jl = lane & 15;       // j-chunk lane
  const float4* t0 = (const float4*)(T + (m0 + 0) * TD);
  const float4* t1 = (const float4*)(T + (m0 + 1) * TD);
  const float4* t2 = (const float4*)(T + (m0 + 2) * TD);
  const float4* t3 = (const float4*)(T + (m0 + 3) * TD);
  const float4* crow = cshr + r * PAD4;
  float a0 = 0.f, a1 = 0.f, a2 = 0.f, a3 = 0.f;
#pragma unroll 2
  for (int j = jl; j < ND4; j += 16) {
    float4 cv = crow[j];
    float4 tv;
    tv = t0[j];
    a0 += fminf(cv.x, tv.x) + fminf(cv.y, tv.y) + fminf(cv.z, tv.z) + fminf(cv.w, tv.w);
    tv = t1[j];
    a1 += fminf(cv.x, tv.x) + fminf(cv.y, tv.y) + fminf(cv.z, tv.z) + fminf(cv.w, tv.w);
    tv = t2[j];
    a2 += fminf(cv.x, tv.x) + fminf(cv.y, tv.y) + fminf(cv.z, tv.z) + fminf(cv.w, tv.w);
    tv = t3[j];
    a3 += fminf(cv.x, tv.x) + fminf(cv.y, tv.y) + fminf(cv.z, tv.z) + fminf(cv.w, tv.w);
  }
  // reduce over jl (lane bits 0-3) within each 16-lane row group
#pragma unroll
  for (int off = 1; off < 16; off <<= 1) {
    a0 += __shfl_xor(a0, off, 64);
    a1 += __shfl_xor(a1, off, 64);
    a2 += __shfl_xor(a2, off, 64);
    a3 += __shfl_xor(a3, off, 64);
  }
  if (jl == 0) {
    float sc;
    sc = ws[512 + m0 + 0];
    if (sc > 0.f) atomicMax(&clsmax[r][labels[m0 + 0]], __float_as_int(a0 * sc));
    sc = ws[512 + m0 + 1];
    if (sc > 0.f) atomicMax(&clsmax[r][labels[m0 + 1]], __float_as_int(a1 * sc));
    sc = ws[512 + m0 + 2];
    if (sc > 0.f) atomicMax(&clsmax[r][labels[m0 + 2]], __float_as_int(a2 * sc));
    sc = ws[512 + m0 + 3];
    if (sc > 0.f) atomicMax(&clsmax[r][labels[m0 + 3]], __float_as_int(a3 * sc));
  }
  __syncthreads();
  // ---- epilogue: combine across the 8 template-group blocks ----
  if (tid < 4 * NCLS) {
    int rr = tid / NCLS, c = tid - rr * NCLS;
    int bits = clsmax[rr][c];
    if (bits != 0xFF800000)
      atomicMax(&out_bits[(row0 + rr) * NCLS + c], bits);
  }
}

extern "C" void kernel_launch(void* const* d_in, const int* in_sizes, int n_in,
                              void* d_out, int out_size, void* d_ws, size_t ws_size,
                              hipStream_t stream) {
  const float* x = (const float*)d_in[0];
  const float* T = (const float*)d_in[1];
  const int* committed = (const int*)d_in[2];
  const int* labels = (const int*)d_in[3];
  const int* counts = (const int*)d_in[4];
  int* out_bits = (int*)d_out;
  float* ws = (float*)d_ws;

  k_minmax<<<dim3(256), dim3(256), 0, stream>>>(x, ws, out_bits);
  k_denom<<<dim3(256), dim3(64), 0, stream>>>(T, committed, counts, ws + 512);
  k_main<<<dim3(2048), dim3(512), 0, stream>>>(x, T, labels, ws, out_bits);
}